// Round 4
// baseline (411.500 us; speedup 1.0000x reference)
//
#include <hip/hip_runtime.h>

// GCN layer: h = x@W + b; pre[i] = sum_{e: row_e==i} w_e * h[col_e]; out = elu(pre)
// d_out = [pre (N*H fp32) | elu(pre) (N*H fp32)]
//
// R4: (a) two-level bucket sort (bucket=row>>6) replaces scattered permute
//     (82 MB write-amp -> ~15 MB); edge payload packed in one u64.
//     (b) gemm register-blocked: x-only LDS (pitch 100 floats, conflict-free),
//     W from global (L2-resident broadcast), 8 rows x float4 per thread.

#define D 96
#define CG 24              // float4 col-groups per row
#define GROUPS_PER_BLOCK 8 // gather: 32-thread groups per 256-block
#define CHUNK 2048         // scan chunk
#define BSHIFT 6
#define BROWS 64           // rows per bucket
// gemm tile
#define GR 64              // rows per block
#define GT 192             // threads (24 cg x 8 rq)
#define XPITCH 25          // float4 pitch of sX row (100 floats; bank-spread)

// ---------------- Kernel 1: h = x @ W + b ----------------
__global__ __launch_bounds__(GT) void gemm_bias_kernel(
    const float* __restrict__ x, const float4* __restrict__ W4,
    const float* __restrict__ b, float* __restrict__ h, int n_nodes) {
  __shared__ float4 sX[GR * XPITCH];  // 25.6 KB
  const int tid = threadIdx.x;
  const int row0 = blockIdx.x * GR;

  for (int i = tid; i < GR * CG; i += GT) {
    const int r = i / CG, c = i % CG;
    float4 v = make_float4(0.f, 0.f, 0.f, 0.f);
    const int gr = row0 + r;
    if (gr < n_nodes) v = ((const float4*)x)[(size_t)gr * CG + c];
    sX[r * XPITCH + c] = v;
  }
  __syncthreads();

  const int cg = tid >> 3;  // 0..23
  const int rq = tid & 7;   // 0..7
  float4 acc[8];
  const float4 bias = ((const float4*)b)[cg];
#pragma unroll
  for (int j = 0; j < 8; ++j) acc[j] = bias;

#define FMA4(A, XS, WV) \
  A.x = fmaf(XS, WV.x, A.x); A.y = fmaf(XS, WV.y, A.y); \
  A.z = fmaf(XS, WV.z, A.z); A.w = fmaf(XS, WV.w, A.w);

  for (int kb = 0; kb < 24; ++kb) {
    const float4 w0 = W4[(kb * 4 + 0) * CG + cg];
    const float4 w1 = W4[(kb * 4 + 1) * CG + cg];
    const float4 w2 = W4[(kb * 4 + 2) * CG + cg];
    const float4 w3 = W4[(kb * 4 + 3) * CG + cg];
#pragma unroll
    for (int j = 0; j < 8; ++j) {
      const float4 xv = sX[(rq + 8 * j) * XPITCH + kb];
      FMA4(acc[j], xv.x, w0);
      FMA4(acc[j], xv.y, w1);
      FMA4(acc[j], xv.z, w2);
      FMA4(acc[j], xv.w, w3);
    }
  }
#pragma unroll
  for (int j = 0; j < 8; ++j) {
    const int r = row0 + rq + 8 * j;
    if (r < n_nodes) ((float4*)h)[(size_t)r * CG + cg] = acc[j];
  }
}

// ---------------- Kernel 2a: histogram of destination rows ----------------
__global__ __launch_bounds__(256) void hist_kernel(
    const int* __restrict__ rows, int* __restrict__ counts, int n_edges) {
  const int e = blockIdx.x * 256 + threadIdx.x;
  if (e < n_edges) atomicAdd(&counts[rows[e]], 1);
}

// ---------------- scan: per-chunk sums ----------------
__global__ __launch_bounds__(256) void block_sum_kernel(
    const int* __restrict__ counts, int* __restrict__ bsum, int n) {
  __shared__ int red[256];
  const int tid = threadIdx.x;
  const int base = blockIdx.x * CHUNK;
  int s = 0;
#pragma unroll
  for (int j = 0; j < 8; ++j) {
    const int i = base + j * 256 + tid;
    if (i < n) s += counts[i];
  }
  red[tid] = s;
  __syncthreads();
  for (int off = 128; off > 0; off >>= 1) {
    if (tid < off) red[tid] += red[tid + off];
    __syncthreads();
  }
  if (tid == 0) bsum[blockIdx.x] = red[0];
}

// ---------------- scan of chunk sums (nb <= 256) ----------------
__global__ __launch_bounds__(256) void scan_bsum_kernel(int* __restrict__ bsum, int nb) {
  __shared__ int buf[256];
  const int tid = threadIdx.x;
  const int v = (tid < nb) ? bsum[tid] : 0;
  buf[tid] = v;
  __syncthreads();
  for (int off = 1; off < 256; off <<= 1) {
    const int t = (tid >= off) ? buf[tid - off] : 0;
    __syncthreads();
    buf[tid] += t;
    __syncthreads();
  }
  if (tid < nb) bsum[tid] = buf[tid] - v;
}

// ---------------- per-chunk exclusive scan + offset; also init bucket cursors
__global__ __launch_bounds__(256) void scan_chunk_kernel(
    const int* __restrict__ counts, const int* __restrict__ bsum,
    int* __restrict__ seg, int* __restrict__ cursor,
    int* __restrict__ bcur, int n) {
  __shared__ int tsum[256];
  const int tid = threadIdx.x;
  const int base = blockIdx.x * CHUNK + tid * 8;
  int v[8];
  int s = 0;
#pragma unroll
  for (int j = 0; j < 8; ++j) {
    const int i = base + j;
    v[j] = (i < n) ? counts[i] : 0;
    s += v[j];
  }
  tsum[tid] = s;
  __syncthreads();
  const int mysum = s;
  for (int off = 1; off < 256; off <<= 1) {
    const int t = (tid >= off) ? tsum[tid - off] : 0;
    __syncthreads();
    tsum[tid] += t;
    __syncthreads();
  }
  int excl = tsum[tid] - mysum + bsum[blockIdx.x];
#pragma unroll
  for (int j = 0; j < 8; ++j) {
    const int i = base + j;
    if (i < n) {
      seg[i] = excl;
      cursor[i] = excl;
      if ((i & (BROWS - 1)) == 0) bcur[i >> BSHIFT] = excl;
    }
    excl += v[j];
  }
}

// ---------------- Pass 1: append edges to row-buckets (packed u64) ----------
// u64 layout: [63:32]=w bits, [21:16]=row low 6 bits, [15:0]=col (n_nodes<65536)
__global__ __launch_bounds__(256) void bucketize_kernel(
    const int* __restrict__ rows, const int* __restrict__ cols,
    const float* __restrict__ ew, int* __restrict__ bcur,
    unsigned long long* __restrict__ tmp, int n_edges) {
  const int e = blockIdx.x * 256 + threadIdx.x;
  if (e >= n_edges) return;
  const int r = rows[e];
  const unsigned int wb = __float_as_uint(ew[e]);
  const unsigned long long u =
      ((unsigned long long)wb << 32) |
      (unsigned long long)(((r & (BROWS - 1)) << 16) | (cols[e] & 0xFFFF));
  const int pos = atomicAdd(&bcur[r >> BSHIFT], 1);
  tmp[pos] = u;
}

// ---------------- Pass 2: within-bucket scatter to exact CSR position -------
__global__ __launch_bounds__(256) void bucket_scatter_kernel(
    const int* __restrict__ seg, int* __restrict__ cursor,
    const unsigned long long* __restrict__ tmp,
    unsigned long long* __restrict__ ps, int n_nodes, int n_edges, int nbkt) {
  const int b = blockIdx.x;
  const int s = seg[b << BSHIFT];
  const int e = (b == nbkt - 1) ? n_edges : seg[(b + 1) << BSHIFT];
  const int rbase = b << BSHIFT;
  for (int k = s + threadIdx.x; k < e; k += 256) {
    const unsigned long long u = tmp[k];
    const int r = rbase + (int)((u >> 16) & (BROWS - 1));
    const int pos = atomicAdd(&cursor[r], 1);
    ps[pos] = u;
  }
}

// ---------------- Kernel 3: per-row gather + accumulate + fused ELU ----------
__global__ __launch_bounds__(256) void gather_kernel(
    const int* __restrict__ seg_start, const int* __restrict__ counts,
    const unsigned long long* __restrict__ ps,
    const float* __restrict__ h, float* __restrict__ pre,
    float* __restrict__ out, int n_nodes) {
  const int g = threadIdx.x >> 5;
  const int lane = threadIdx.x & 31;
  const int row = blockIdx.x * GROUPS_PER_BLOCK + g;
  if (row >= n_nodes) return;
  const int s = seg_start[row];
  const int e = s + counts[row];
  float a0 = 0.f, a1 = 0.f, a2 = 0.f;
  int k = s;
  for (; k + 1 < e; k += 2) {
    const unsigned long long u0 = ps[k], u1 = ps[k + 1];
    const int c0 = (int)(u0 & 0xFFFF), c1 = (int)(u1 & 0xFFFF);
    const float w0 = __uint_as_float((unsigned int)(u0 >> 32));
    const float w1 = __uint_as_float((unsigned int)(u1 >> 32));
    const float* h0 = h + (size_t)c0 * D;
    const float* h1 = h + (size_t)c1 * D;
    const float p00 = h0[lane], p01 = h0[lane + 32], p02 = h0[lane + 64];
    const float p10 = h1[lane], p11 = h1[lane + 32], p12 = h1[lane + 64];
    a0 = fmaf(w0, p00, a0); a1 = fmaf(w0, p01, a1); a2 = fmaf(w0, p02, a2);
    a0 = fmaf(w1, p10, a0); a1 = fmaf(w1, p11, a1); a2 = fmaf(w1, p12, a2);
  }
  if (k < e) {
    const unsigned long long u = ps[k];
    const int c = (int)(u & 0xFFFF);
    const float w = __uint_as_float((unsigned int)(u >> 32));
    const float* hr = h + (size_t)c * D;
    a0 = fmaf(w, hr[lane], a0);
    a1 = fmaf(w, hr[lane + 32], a1);
    a2 = fmaf(w, hr[lane + 64], a2);
  }
  float* pr = pre + (size_t)row * D;
  float* orow = out + (size_t)row * D;
  pr[lane] = a0; pr[lane + 32] = a1; pr[lane + 64] = a2;
  orow[lane]      = a0 > 0.f ? a0 : (__expf(a0) - 1.f);
  orow[lane + 32] = a1 > 0.f ? a1 : (__expf(a1) - 1.f);
  orow[lane + 64] = a2 > 0.f ? a2 : (__expf(a2) - 1.f);
}

extern "C" void kernel_launch(void* const* d_in, const int* in_sizes, int n_in,
                              void* d_out, int out_size, void* d_ws, size_t ws_size,
                              hipStream_t stream) {
  const float* x  = (const float*)d_in[0];
  const float* W  = (const float*)d_in[1];
  const float* b  = (const float*)d_in[2];
  const int*   ei = (const int*)d_in[3];
  const float* ew = (const float*)d_in[4];

  const int n_nodes = in_sizes[0] / D;
  const int n_edges = in_sizes[4];
  const int* rows = ei;
  const int* cols = ei + n_edges;

  float* pre  = (float*)d_out;
  float* outp = pre + (size_t)n_nodes * D;

  const int nbkt = (n_nodes + BROWS - 1) / BROWS;

  // workspace layout (~32.7 MB)
  char* ws = (char*)d_ws;
  float* h      = (float*)ws;  ws += (size_t)n_nodes * D * sizeof(float);
  int*   counts = (int*)ws;    ws += (size_t)n_nodes * sizeof(int);
  int*   seg    = (int*)ws;    ws += (size_t)n_nodes * sizeof(int);
  int*   cursor = (int*)ws;    ws += (size_t)n_nodes * sizeof(int);
  int*   bsum   = (int*)ws;    ws += 256 * sizeof(int);
  int*   bcur   = (int*)ws;    ws += (size_t)((nbkt + 63) & ~63) * sizeof(int);
  unsigned long long* tmp = (unsigned long long*)ws;
  ws += (size_t)n_edges * sizeof(unsigned long long);
  unsigned long long* ps  = (unsigned long long*)ws;

  hipMemsetAsync(counts, 0, (size_t)n_nodes * sizeof(int), stream);

  const int gemm_blocks = (n_nodes + GR - 1) / GR;
  gemm_bias_kernel<<<gemm_blocks, GT, 0, stream>>>(x, (const float4*)W, b, h, n_nodes);

  const int eb = (n_edges + 255) / 256;
  hist_kernel<<<eb, 256, 0, stream>>>(rows, counts, n_edges);

  const int nb = (n_nodes + CHUNK - 1) / CHUNK;
  block_sum_kernel<<<nb, 256, 0, stream>>>(counts, bsum, n_nodes);
  scan_bsum_kernel<<<1, 256, 0, stream>>>(bsum, nb);
  scan_chunk_kernel<<<nb, 256, 0, stream>>>(counts, bsum, seg, cursor, bcur, n_nodes);

  bucketize_kernel<<<eb, 256, 0, stream>>>(rows, cols, ew, bcur, tmp, n_edges);
  bucket_scatter_kernel<<<nbkt, 256, 0, stream>>>(seg, cursor, tmp, ps, n_nodes, n_edges, nbkt);

  const int gb = (n_nodes + GROUPS_PER_BLOCK - 1) / GROUPS_PER_BLOCK;
  gather_kernel<<<gb, 256, 0, stream>>>(seg, counts, ps, h, pre, outp, n_nodes);
}

// Round 5
// 268.496 us; speedup vs baseline: 1.5326x; 1.5326x over previous
//
#include <hip/hip_runtime.h>

// GCN layer: h = x@W + b; pre[i] = sum_{e: row_e==i} w_e * h[col_e]; out = elu(pre)
// d_out = [pre (N*H fp32) | elu(pre) (N*H fp32)]
//
// R5: fix R4's atomic false-sharing — each bucket cursor gets its own 128B
// line (stride 32 ints). 800K atomics now spread over 782 lines, not 49.

#define D 96
#define CG 24              // float4 col-groups per row
#define GROUPS_PER_BLOCK 8 // gather: 32-thread groups per 256-block
#define CHUNK 2048         // scan chunk
#define BSHIFT 6
#define BROWS 64           // rows per bucket
#define CPAD 32            // ints per bucket cursor (128B line)
// gemm tile
#define GR 64              // rows per block
#define GT 192             // threads (24 cg x 8 rq)
#define XPITCH 25          // float4 pitch of sX row (100 floats; bank-spread)

// ---------------- Kernel 1: h = x @ W + b ----------------
__global__ __launch_bounds__(GT) void gemm_bias_kernel(
    const float* __restrict__ x, const float4* __restrict__ W4,
    const float* __restrict__ b, float* __restrict__ h, int n_nodes) {
  __shared__ float4 sX[GR * XPITCH];  // 25.6 KB
  const int tid = threadIdx.x;
  const int row0 = blockIdx.x * GR;

  for (int i = tid; i < GR * CG; i += GT) {
    const int r = i / CG, c = i % CG;
    float4 v = make_float4(0.f, 0.f, 0.f, 0.f);
    const int gr = row0 + r;
    if (gr < n_nodes) v = ((const float4*)x)[(size_t)gr * CG + c];
    sX[r * XPITCH + c] = v;
  }
  __syncthreads();

  const int cg = tid >> 3;  // 0..23
  const int rq = tid & 7;   // 0..7
  float4 acc[8];
  const float4 bias = ((const float4*)b)[cg];
#pragma unroll
  for (int j = 0; j < 8; ++j) acc[j] = bias;

#define FMA4(A, XS, WV) \
  A.x = fmaf(XS, WV.x, A.x); A.y = fmaf(XS, WV.y, A.y); \
  A.z = fmaf(XS, WV.z, A.z); A.w = fmaf(XS, WV.w, A.w);

  for (int kb = 0; kb < 24; ++kb) {
    const float4 w0 = W4[(kb * 4 + 0) * CG + cg];
    const float4 w1 = W4[(kb * 4 + 1) * CG + cg];
    const float4 w2 = W4[(kb * 4 + 2) * CG + cg];
    const float4 w3 = W4[(kb * 4 + 3) * CG + cg];
#pragma unroll
    for (int j = 0; j < 8; ++j) {
      const float4 xv = sX[(rq + 8 * j) * XPITCH + kb];
      FMA4(acc[j], xv.x, w0);
      FMA4(acc[j], xv.y, w1);
      FMA4(acc[j], xv.z, w2);
      FMA4(acc[j], xv.w, w3);
    }
  }
#pragma unroll
  for (int j = 0; j < 8; ++j) {
    const int r = row0 + rq + 8 * j;
    if (r < n_nodes) ((float4*)h)[(size_t)r * CG + cg] = acc[j];
  }
}

// ---------------- Kernel 2a: histogram of destination rows ----------------
__global__ __launch_bounds__(256) void hist_kernel(
    const int* __restrict__ rows, int* __restrict__ counts, int n_edges) {
  const int e = blockIdx.x * 256 + threadIdx.x;
  if (e < n_edges) atomicAdd(&counts[rows[e]], 1);
}

// ---------------- scan: per-chunk sums ----------------
__global__ __launch_bounds__(256) void block_sum_kernel(
    const int* __restrict__ counts, int* __restrict__ bsum, int n) {
  __shared__ int red[256];
  const int tid = threadIdx.x;
  const int base = blockIdx.x * CHUNK;
  int s = 0;
#pragma unroll
  for (int j = 0; j < 8; ++j) {
    const int i = base + j * 256 + tid;
    if (i < n) s += counts[i];
  }
  red[tid] = s;
  __syncthreads();
  for (int off = 128; off > 0; off >>= 1) {
    if (tid < off) red[tid] += red[tid + off];
    __syncthreads();
  }
  if (tid == 0) bsum[blockIdx.x] = red[0];
}

// ---------------- scan of chunk sums (nb <= 256) ----------------
__global__ __launch_bounds__(256) void scan_bsum_kernel(int* __restrict__ bsum, int nb) {
  __shared__ int buf[256];
  const int tid = threadIdx.x;
  const int v = (tid < nb) ? bsum[tid] : 0;
  buf[tid] = v;
  __syncthreads();
  for (int off = 1; off < 256; off <<= 1) {
    const int t = (tid >= off) ? buf[tid - off] : 0;
    __syncthreads();
    buf[tid] += t;
    __syncthreads();
  }
  if (tid < nb) bsum[tid] = buf[tid] - v;
}

// ---------------- per-chunk exclusive scan + offset; also init bucket cursors
__global__ __launch_bounds__(256) void scan_chunk_kernel(
    const int* __restrict__ counts, const int* __restrict__ bsum,
    int* __restrict__ seg, int* __restrict__ cursor,
    int* __restrict__ bcur, int n) {
  __shared__ int tsum[256];
  const int tid = threadIdx.x;
  const int base = blockIdx.x * CHUNK + tid * 8;
  int v[8];
  int s = 0;
#pragma unroll
  for (int j = 0; j < 8; ++j) {
    const int i = base + j;
    v[j] = (i < n) ? counts[i] : 0;
    s += v[j];
  }
  tsum[tid] = s;
  __syncthreads();
  const int mysum = s;
  for (int off = 1; off < 256; off <<= 1) {
    const int t = (tid >= off) ? tsum[tid - off] : 0;
    __syncthreads();
    tsum[tid] += t;
    __syncthreads();
  }
  int excl = tsum[tid] - mysum + bsum[blockIdx.x];
#pragma unroll
  for (int j = 0; j < 8; ++j) {
    const int i = base + j;
    if (i < n) {
      seg[i] = excl;
      cursor[i] = excl;
      if ((i & (BROWS - 1)) == 0) bcur[(i >> BSHIFT) * CPAD] = excl;
    }
    excl += v[j];
  }
}

// ---------------- Pass 1: append edges to row-buckets (packed u64) ----------
// u64 layout: [63:32]=w bits, [21:16]=row low 6 bits, [15:0]=col (n_nodes<65536)
__global__ __launch_bounds__(256) void bucketize_kernel(
    const int* __restrict__ rows, const int* __restrict__ cols,
    const float* __restrict__ ew, int* __restrict__ bcur,
    unsigned long long* __restrict__ tmp, int n_edges) {
  const int e = blockIdx.x * 256 + threadIdx.x;
  if (e >= n_edges) return;
  const int r = rows[e];
  const unsigned int wb = __float_as_uint(ew[e]);
  const unsigned long long u =
      ((unsigned long long)wb << 32) |
      (unsigned long long)(((r & (BROWS - 1)) << 16) | (cols[e] & 0xFFFF));
  const int pos = atomicAdd(&bcur[(r >> BSHIFT) * CPAD], 1);
  tmp[pos] = u;
}

// ---------------- Pass 2: within-bucket scatter to exact CSR position -------
__global__ __launch_bounds__(256) void bucket_scatter_kernel(
    const int* __restrict__ seg, int* __restrict__ cursor,
    const unsigned long long* __restrict__ tmp,
    unsigned long long* __restrict__ ps, int n_nodes, int n_edges, int nbkt) {
  const int b = blockIdx.x;
  const int s = seg[b << BSHIFT];
  const int e = (b == nbkt - 1) ? n_edges : seg[(b + 1) << BSHIFT];
  const int rbase = b << BSHIFT;
  for (int k = s + threadIdx.x; k < e; k += 256) {
    const unsigned long long u = tmp[k];
    const int r = rbase + (int)((u >> 16) & (BROWS - 1));
    const int pos = atomicAdd(&cursor[r], 1);
    ps[pos] = u;
  }
}

// ---------------- Kernel 3: per-row gather + accumulate + fused ELU ----------
__global__ __launch_bounds__(256) void gather_kernel(
    const int* __restrict__ seg_start, const int* __restrict__ counts,
    const unsigned long long* __restrict__ ps,
    const float* __restrict__ h, float* __restrict__ pre,
    float* __restrict__ out, int n_nodes) {
  const int g = threadIdx.x >> 5;
  const int lane = threadIdx.x & 31;
  const int row = blockIdx.x * GROUPS_PER_BLOCK + g;
  if (row >= n_nodes) return;
  const int s = seg_start[row];
  const int e = s + counts[row];
  float a0 = 0.f, a1 = 0.f, a2 = 0.f;
  int k = s;
  for (; k + 1 < e; k += 2) {
    const unsigned long long u0 = ps[k], u1 = ps[k + 1];
    const int c0 = (int)(u0 & 0xFFFF), c1 = (int)(u1 & 0xFFFF);
    const float w0 = __uint_as_float((unsigned int)(u0 >> 32));
    const float w1 = __uint_as_float((unsigned int)(u1 >> 32));
    const float* h0 = h + (size_t)c0 * D;
    const float* h1 = h + (size_t)c1 * D;
    const float p00 = h0[lane], p01 = h0[lane + 32], p02 = h0[lane + 64];
    const float p10 = h1[lane], p11 = h1[lane + 32], p12 = h1[lane + 64];
    a0 = fmaf(w0, p00, a0); a1 = fmaf(w0, p01, a1); a2 = fmaf(w0, p02, a2);
    a0 = fmaf(w1, p10, a0); a1 = fmaf(w1, p11, a1); a2 = fmaf(w1, p12, a2);
  }
  if (k < e) {
    const unsigned long long u = ps[k];
    const int c = (int)(u & 0xFFFF);
    const float w = __uint_as_float((unsigned int)(u >> 32));
    const float* hr = h + (size_t)c * D;
    a0 = fmaf(w, hr[lane], a0);
    a1 = fmaf(w, hr[lane + 32], a1);
    a2 = fmaf(w, hr[lane + 64], a2);
  }
  float* pr = pre + (size_t)row * D;
  float* orow = out + (size_t)row * D;
  pr[lane] = a0; pr[lane + 32] = a1; pr[lane + 64] = a2;
  orow[lane]      = a0 > 0.f ? a0 : (__expf(a0) - 1.f);
  orow[lane + 32] = a1 > 0.f ? a1 : (__expf(a1) - 1.f);
  orow[lane + 64] = a2 > 0.f ? a2 : (__expf(a2) - 1.f);
}

extern "C" void kernel_launch(void* const* d_in, const int* in_sizes, int n_in,
                              void* d_out, int out_size, void* d_ws, size_t ws_size,
                              hipStream_t stream) {
  const float* x  = (const float*)d_in[0];
  const float* W  = (const float*)d_in[1];
  const float* b  = (const float*)d_in[2];
  const int*   ei = (const int*)d_in[3];
  const float* ew = (const float*)d_in[4];

  const int n_nodes = in_sizes[0] / D;
  const int n_edges = in_sizes[4];
  const int* rows = ei;
  const int* cols = ei + n_edges;

  float* pre  = (float*)d_out;
  float* outp = pre + (size_t)n_nodes * D;

  const int nbkt = (n_nodes + BROWS - 1) / BROWS;

  // workspace layout (~33 MB)
  char* ws = (char*)d_ws;
  float* h      = (float*)ws;  ws += (size_t)n_nodes * D * sizeof(float);
  int*   counts = (int*)ws;    ws += (size_t)n_nodes * sizeof(int);
  int*   seg    = (int*)ws;    ws += (size_t)n_nodes * sizeof(int);
  int*   cursor = (int*)ws;    ws += (size_t)n_nodes * sizeof(int);
  int*   bsum   = (int*)ws;    ws += 256 * sizeof(int);
  int*   bcur   = (int*)ws;    ws += (size_t)nbkt * CPAD * sizeof(int);
  unsigned long long* tmp = (unsigned long long*)ws;
  ws += (size_t)n_edges * sizeof(unsigned long long);
  unsigned long long* ps  = (unsigned long long*)ws;

  hipMemsetAsync(counts, 0, (size_t)n_nodes * sizeof(int), stream);

  const int gemm_blocks = (n_nodes + GR - 1) / GR;
  gemm_bias_kernel<<<gemm_blocks, GT, 0, stream>>>(x, (const float4*)W, b, h, n_nodes);

  const int eb = (n_edges + 255) / 256;
  hist_kernel<<<eb, 256, 0, stream>>>(rows, counts, n_edges);

  const int nb = (n_nodes + CHUNK - 1) / CHUNK;
  block_sum_kernel<<<nb, 256, 0, stream>>>(counts, bsum, n_nodes);
  scan_bsum_kernel<<<1, 256, 0, stream>>>(bsum, nb);
  scan_chunk_kernel<<<nb, 256, 0, stream>>>(counts, bsum, seg, cursor, bcur, n_nodes);

  bucketize_kernel<<<eb, 256, 0, stream>>>(rows, cols, ew, bcur, tmp, n_edges);
  bucket_scatter_kernel<<<nbkt, 256, 0, stream>>>(seg, cursor, tmp, ps, n_nodes, n_edges, nbkt);

  const int gb = (n_nodes + GROUPS_PER_BLOCK - 1) / GROUPS_PER_BLOCK;
  gather_kernel<<<gb, 256, 0, stream>>>(seg, counts, ps, h, pre, outp, n_nodes);
}